// Round 3
// baseline (137.778 us; speedup 1.0000x reference)
//
#include <hip/hip_runtime.h>
#include <math.h>

#define N_EMBD    4096
#define N_EXPERTS 64
#define N_TOKENS  16384
#define TAU       1e-3f

typedef __attribute__((ext_vector_type(8))) short bf16x8;
typedef __attribute__((ext_vector_type(4))) float f32x4;

#define MFMA16 __builtin_amdgcn_mfma_f32_16x16x32_bf16

// ---------------------------------------------------------------------------
// f32 -> (bf16 hi, bf16 lo) split, RNE, pair-packed into one u32 each.
// x = hi + lo + err, |err| ~ 2^-18 |x|.
// ---------------------------------------------------------------------------
__device__ __forceinline__ void split_pair(float f0, float f1,
                                           unsigned& hpack, unsigned& lpack) {
    unsigned u0 = __builtin_bit_cast(unsigned, f0);
    unsigned u1 = __builtin_bit_cast(unsigned, f1);
    unsigned r0 = u0 + 0x7FFFu + ((u0 >> 16) & 1u);
    unsigned r1 = u1 + 0x7FFFu + ((u1 >> 16) & 1u);
    hpack = (r0 >> 16) | (r1 & 0xFFFF0000u);
    float h0 = __builtin_bit_cast(float, r0 & 0xFFFF0000u);
    float h1 = __builtin_bit_cast(float, r1 & 0xFFFF0000u);
    float l0 = f0 - h0;
    float l1 = f1 - h1;
    unsigned v0 = __builtin_bit_cast(unsigned, l0);
    unsigned v1 = __builtin_bit_cast(unsigned, l1);
    unsigned s0 = v0 + 0x7FFFu + ((v0 >> 16) & 1u);
    unsigned s1 = v1 + 0x7FFFu + ((v1 >> 16) & 1u);
    lpack = (s0 >> 16) | (s1 & 0xFFFF0000u);
}

// ---------------------------------------------------------------------------
// Kernel 0: pack W into bf16 hi/lo MFMA B-fragments; zero the flag counter.
// Frag F = ks*8 + nt*2 + term (ks = K-step of 32, nt = expert tile of 16,
// term 0=hi 1=lo). Lane l elem j holds W[nt*16+(l&15)][ks*32+(l>>4)*8+j].
// ---------------------------------------------------------------------------
__global__ void w_pack_bf16(const float* __restrict__ W,
                            uint4* __restrict__ Bpack,
                            int* __restrict__ flags) {
    int tid = blockIdx.x * blockDim.x + threadIdx.x;   // 32768
    if (tid == 0) flags[0] = 0;
    int lane = tid & 63;
    int nt   = (tid >> 6) & 3;
    int ks   = tid >> 8;                               // 0..127
    int e = nt * 16 + (lane & 15);
    int k = ks * 32 + ((lane >> 4) << 3);
    const float* src = W + (size_t)e * N_EMBD + k;
    uint4 hp, lp;
    split_pair(src[0], src[1], hp.x, lp.x);
    split_pair(src[2], src[3], hp.y, lp.y);
    split_pair(src[4], src[5], hp.z, lp.z);
    split_pair(src[6], src[7], hp.w, lp.w);
    size_t F = (size_t)ks * 8 + nt * 2;
    Bpack[F * 64 + lane]       = hp;
    Bpack[(F + 1) * 64 + lane] = lp;
}

// ---------------------------------------------------------------------------
// One K-step: split A to hi/lo, 12 MFMAs (4 N-tiles x {hi*hi, hi*lo, lo*hi})
// ---------------------------------------------------------------------------
__device__ __forceinline__ void compute_step(
        float4 A0, float4 A1,
        uint4 B0, uint4 B1, uint4 B2, uint4 B3,
        uint4 B4, uint4 B5, uint4 B6, uint4 B7,
        f32x4& c0, f32x4& c1, f32x4& c2, f32x4& c3) {
    uint4 hu, lu;
    split_pair(A0.x, A0.y, hu.x, lu.x);
    split_pair(A0.z, A0.w, hu.y, lu.y);
    split_pair(A1.x, A1.y, hu.z, lu.z);
    split_pair(A1.z, A1.w, hu.w, lu.w);
    bf16x8 ah = __builtin_bit_cast(bf16x8, hu);
    bf16x8 al = __builtin_bit_cast(bf16x8, lu);
    bf16x8 bh, bl;
    bh = __builtin_bit_cast(bf16x8, B0); bl = __builtin_bit_cast(bf16x8, B1);
    c0 = MFMA16(ah, bh, c0, 0, 0, 0);
    c0 = MFMA16(ah, bl, c0, 0, 0, 0);
    c0 = MFMA16(al, bh, c0, 0, 0, 0);
    bh = __builtin_bit_cast(bf16x8, B2); bl = __builtin_bit_cast(bf16x8, B3);
    c1 = MFMA16(ah, bh, c1, 0, 0, 0);
    c1 = MFMA16(ah, bl, c1, 0, 0, 0);
    c1 = MFMA16(al, bh, c1, 0, 0, 0);
    bh = __builtin_bit_cast(bf16x8, B4); bl = __builtin_bit_cast(bf16x8, B5);
    c2 = MFMA16(ah, bh, c2, 0, 0, 0);
    c2 = MFMA16(ah, bl, c2, 0, 0, 0);
    c2 = MFMA16(al, bh, c2, 0, 0, 0);
    bh = __builtin_bit_cast(bf16x8, B6); bl = __builtin_bit_cast(bf16x8, B7);
    c3 = MFMA16(ah, bh, c3, 0, 0, 0);
    c3 = MFMA16(ah, bl, c3, 0, 0, 0);
    c3 = MFMA16(al, bh, c3, 0, 0, 0);
}

// ---------------------------------------------------------------------------
// Kernel 1: fused router. Block = 4 waves = 4 K-quarters of ONE 16-token
// group. No main-loop barriers (B is L2-resident; prefetch stays in flight).
// End: waves 1-3 dump logits to LDS, wave 0 combines + top-3 butterflies
// (within 16-lane groups) + softmax + output + near-tie flagging.
// ---------------------------------------------------------------------------
__global__ __launch_bounds__(256, 4) void router_fused(
        const float* __restrict__ x,
        const uint4* __restrict__ Bpack,
        float* __restrict__ out,
        int* __restrict__ flags) {
    __shared__ float red[3][16][64];
    const int lane = threadIdx.x & 63;
    const int kq   = threadIdx.x >> 6;        // K-quarter 0..3
    const int tok0 = blockIdx.x * 16;

    const float4* pa = (const float4*)x
        + (size_t)(tok0 + (lane & 15)) * (N_EMBD / 4)
        + kq * 256 + ((lane >> 4) << 1);
    const uint4* pb = Bpack + (size_t)kq * 16384 + lane;

    f32x4 acc0 = {0.f,0.f,0.f,0.f}, acc1 = {0.f,0.f,0.f,0.f};
    f32x4 acc2 = {0.f,0.f,0.f,0.f}, acc3 = {0.f,0.f,0.f,0.f};

    uint4 ba0, ba1, ba2, ba3, ba4, ba5, ba6, ba7;
    uint4 bb0, bb1, bb2, bb3, bb4, bb5, bb6, bb7;
    float4 a0a, a1a, a0b, a1b;

#define LOADB(P, s) { const uint4* _q = pb + (size_t)(s) * 512;               \
    P##0 = _q[0];   P##1 = _q[64];  P##2 = _q[128]; P##3 = _q[192];           \
    P##4 = _q[256]; P##5 = _q[320]; P##6 = _q[384]; P##7 = _q[448]; }
#define LOADA(A0, A1, s) { A0 = pa[(s) * 8]; A1 = pa[(s) * 8 + 1]; }

    LOADB(ba, 0); LOADA(a0a, a1a, 0);
    for (int s = 0; s < 32; s += 2) {
        LOADB(bb, s + 1); LOADA(a0b, a1b, s + 1);
        compute_step(a0a, a1a, ba0, ba1, ba2, ba3, ba4, ba5, ba6, ba7,
                     acc0, acc1, acc2, acc3);
        if (s < 30) { LOADB(ba, s + 2); LOADA(a0a, a1a, s + 2); }
        compute_step(a0b, a1b, bb0, bb1, bb2, bb3, bb4, bb5, bb6, bb7,
                     acc0, acc1, acc2, acc3);
    }
#undef LOADB
#undef LOADA

    // C layout: row(token) = (lane>>4)*4 + reg, col(expert base) = lane&15
    const int l15 = lane & 15;
    const int rb  = (lane >> 4) << 2;
    if (kq > 0) {
#pragma unroll
        for (int j = 0; j < 4; ++j) {
            red[kq - 1][rb + j][l15]      = acc0[j];
            red[kq - 1][rb + j][16 + l15] = acc1[j];
            red[kq - 1][rb + j][32 + l15] = acc2[j];
            red[kq - 1][rb + j][48 + l15] = acc3[j];
        }
    }
    __syncthreads();
    if (kq != 0) return;

#pragma unroll
    for (int j = 0; j < 4; ++j) {
        const int t = rb + j;
        float v0 = acc0[j] + red[0][t][l15]      + red[1][t][l15]      + red[2][t][l15];
        float v1 = acc1[j] + red[0][t][16 + l15] + red[1][t][16 + l15] + red[2][t][16 + l15];
        float v2 = acc2[j] + red[0][t][32 + l15] + red[1][t][32 + l15] + red[2][t][32 + l15];
        float v3 = acc3[j] + red[0][t][48 + l15] + red[1][t][48 + l15] + red[2][t][48 + l15];

        // pass A: top-1 (strict > keeps lowest expert index on ties)
        float m1 = v0; int i1 = l15;
        if (v1 > m1) { m1 = v1; i1 = 16 + l15; }
        if (v2 > m1) { m1 = v2; i1 = 32 + l15; }
        if (v3 > m1) { m1 = v3; i1 = 48 + l15; }
#pragma unroll
        for (int off = 8; off; off >>= 1) {
            float ov = __shfl_xor(m1, off); int oi = __shfl_xor(i1, off);
            if (ov > m1 || (ov == m1 && oi < i1)) { m1 = ov; i1 = oi; }
        }
        // pass B: top-2
        float m2 = -INFINITY; int i2 = 64;
        if (i1 != l15      && v0 > m2) { m2 = v0; i2 = l15; }
        if (i1 != 16 + l15 && v1 > m2) { m2 = v1; i2 = 16 + l15; }
        if (i1 != 32 + l15 && v2 > m2) { m2 = v2; i2 = 32 + l15; }
        if (i1 != 48 + l15 && v3 > m2) { m2 = v3; i2 = 48 + l15; }
#pragma unroll
        for (int off = 8; off; off >>= 1) {
            float ov = __shfl_xor(m2, off); int oi = __shfl_xor(i2, off);
            if (ov > m2 || (ov == m2 && oi < i2)) { m2 = ov; i2 = oi; }
        }
        // pass C: top-3 value only (near-tie detector)
        float m3 = -INFINITY;
        if (i1 != l15      && i2 != l15      ) m3 = fmaxf(m3, v0);
        if (i1 != 16 + l15 && i2 != 16 + l15 ) m3 = fmaxf(m3, v1);
        if (i1 != 32 + l15 && i2 != 32 + l15 ) m3 = fmaxf(m3, v2);
        if (i1 != 48 + l15 && i2 != 48 + l15 ) m3 = fmaxf(m3, v3);
#pragma unroll
        for (int off = 8; off; off >>= 1)
            m3 = fmaxf(m3, __shfl_xor(m3, off));

        if (l15 == 0) {
            const int tok = tok0 + t;
            float e2  = __expf(m2 - m1);
            float inv = 1.0f / (1.0f + e2);
            out[2 * tok + 0] = (float)i1;
            out[2 * tok + 1] = (float)i2;
            out[2 * N_TOKENS + 2 * tok + 0] = inv;
            out[2 * N_TOKENS + 2 * tok + 1] = e2 * inv;
            if ((m1 - m2 < TAU) || (m2 - m3 < TAU)) {
                int p = atomicAdd(flags, 1);
                if (p < N_TOKENS) flags[1 + p] = tok;
            }
        }
    }
}

// ---------------------------------------------------------------------------
// Kernel 2: exact f64 refinement of flagged near-tie tokens. Block per token
// (grid-strided). Wave wv handles experts wv*16..wv*16+15, lanes split K.
// ---------------------------------------------------------------------------
__global__ __launch_bounds__(256) void refine(const float* __restrict__ x,
                                              const float* __restrict__ W,
                                              const int* __restrict__ flags,
                                              float* __restrict__ out) {
    __shared__ double redd[64];
    const int lane = threadIdx.x & 63;
    const int wv   = threadIdx.x >> 6;
    int cnt = flags[0];
    if (cnt > N_TOKENS) cnt = N_TOKENS;

    for (int i = blockIdx.x; i < cnt; i += gridDim.x) {
        const int tok = flags[1 + i];
        const float4* xr4 = (const float4*)(x + (size_t)tok * N_EMBD);
#pragma unroll
        for (int ee = 0; ee < 16; ++ee) {
            const int e = wv * 16 + ee;
            const float4* wr = (const float4*)(W + (size_t)e * N_EMBD);
            double acc = 0.0;
#pragma unroll 4
            for (int c = 0; c < 16; ++c) {
                float4 xv = xr4[c * 64 + lane];
                float4 wq = wr[c * 64 + lane];
                acc += (double)xv.x * wq.x + (double)xv.y * wq.y
                     + (double)xv.z * wq.z + (double)xv.w * wq.w;
            }
#pragma unroll
            for (int off = 32; off; off >>= 1)
                acc += __shfl_xor(acc, off);
            if (lane == 0) redd[e] = acc;
        }
        __syncthreads();
        if (wv == 0) {
            double v = redd[lane];
            double m1 = v; int i1 = lane;
#pragma unroll
            for (int off = 32; off; off >>= 1) {
                double ov = __shfl_xor(m1, off); int oi = __shfl_xor(i1, off);
                if (ov > m1 || (ov == m1 && oi < i1)) { m1 = ov; i1 = oi; }
            }
            double m2 = (lane == i1) ? -INFINITY : v; int i2 = lane;
#pragma unroll
            for (int off = 32; off; off >>= 1) {
                double ov = __shfl_xor(m2, off); int oi = __shfl_xor(i2, off);
                if (ov > m2 || (ov == m2 && oi < i2)) { m2 = ov; i2 = oi; }
            }
            if (lane == 0) {
                double e2  = exp(m2 - m1);
                double inv = 1.0 / (1.0 + e2);
                out[2 * tok + 0] = (float)i1;
                out[2 * tok + 1] = (float)i2;
                out[2 * N_TOKENS + 2 * tok + 0] = (float)inv;
                out[2 * N_TOKENS + 2 * tok + 1] = (float)(e2 * inv);
            }
        }
        __syncthreads();
    }
}

// ---------------------------------------------------------------------------
extern "C" void kernel_launch(void* const* d_in, const int* in_sizes, int n_in,
                              void* d_out, int out_size, void* d_ws, size_t ws_size,
                              hipStream_t stream) {
    const float* x = (const float*)d_in[0];
    const float* W = (const float*)d_in[1];
    float* out = (float*)d_out;

    uint4* Bpack = (uint4*)d_ws;                          // [0, 1MB)
    int*   flags = (int*)((char*)d_ws + (2u << 20));      // [2MB, ...)

    w_pack_bf16 <<<128, 256, 0, stream>>>(W, Bpack, flags);
    router_fused<<<N_TOKENS / 16, 256, 0, stream>>>(x, Bpack, out, flags);
    refine      <<<64, 256, 0, stream>>>(x, W, flags, out);
}

// Round 6
// 131.602 us; speedup vs baseline: 1.0469x; 1.0469x over previous
//
#include <hip/hip_runtime.h>
#include <math.h>

#define N_EMBD    4096
#define N_EXPERTS 64
#define N_TOKENS  16384
#define TAU       1e-3f

typedef __attribute__((ext_vector_type(8))) short bf16x8;
typedef __attribute__((ext_vector_type(4))) float f32x4;
typedef __attribute__((ext_vector_type(4))) unsigned u32x4;

#define MFMA16 __builtin_amdgcn_mfma_f32_16x16x32_bf16

struct hl_pair { unsigned h, l; };

// ---------------------------------------------------------------------------
// f32 -> (bf16 hi, bf16 lo) split, RNE, pair-packed into one u32 each.
// x = hi + lo + err, |err| ~ 2^-18 |x|.
// ---------------------------------------------------------------------------
__device__ __forceinline__ hl_pair split_pair(float f0, float f1) {
    unsigned u0 = __builtin_bit_cast(unsigned, f0);
    unsigned u1 = __builtin_bit_cast(unsigned, f1);
    unsigned r0 = u0 + 0x7FFFu + ((u0 >> 16) & 1u);
    unsigned r1 = u1 + 0x7FFFu + ((u1 >> 16) & 1u);
    hl_pair p;
    p.h = (r0 >> 16) | (r1 & 0xFFFF0000u);
    float h0 = __builtin_bit_cast(float, r0 & 0xFFFF0000u);
    float h1 = __builtin_bit_cast(float, r1 & 0xFFFF0000u);
    float l0 = f0 - h0;
    float l1 = f1 - h1;
    unsigned v0 = __builtin_bit_cast(unsigned, l0);
    unsigned v1 = __builtin_bit_cast(unsigned, l1);
    unsigned s0 = v0 + 0x7FFFu + ((v0 >> 16) & 1u);
    unsigned s1 = v1 + 0x7FFFu + ((v1 >> 16) & 1u);
    p.l = (s0 >> 16) | (s1 & 0xFFFF0000u);
    return p;
}

// ---------------------------------------------------------------------------
// Kernel 0: pack W into bf16 hi/lo MFMA B-fragments; zero the flag counter.
// Frag F = ks*8 + nt*2 + term. Lane l elem j = W[nt*16+(l&15)][ks*32+(l>>4)*8+j]
// ---------------------------------------------------------------------------
__global__ void w_pack_bf16(const float* __restrict__ W,
                            uint4* __restrict__ Bpack,
                            int* __restrict__ flags) {
    int tid = blockIdx.x * blockDim.x + threadIdx.x;   // 32768
    if (tid == 0) flags[0] = 0;
    int lane = tid & 63;
    int nt   = (tid >> 6) & 3;
    int ks   = tid >> 8;                               // 0..127
    int e = nt * 16 + (lane & 15);
    int k = ks * 32 + ((lane >> 4) << 3);
    const float* src = W + (size_t)e * N_EMBD + k;
    uint4 hp, lp;
    hl_pair p0 = split_pair(src[0], src[1]);
    hl_pair p1 = split_pair(src[2], src[3]);
    hl_pair p2 = split_pair(src[4], src[5]);
    hl_pair p3 = split_pair(src[6], src[7]);
    hp.x = p0.h; lp.x = p0.l;
    hp.y = p1.h; lp.y = p1.l;
    hp.z = p2.h; lp.z = p2.l;
    hp.w = p3.h; lp.w = p3.l;
    size_t F = (size_t)ks * 8 + nt * 2;
    Bpack[F * 64 + lane]       = hp;
    Bpack[(F + 1) * 64 + lane] = lp;
}

// ---------------------------------------------------------------------------
// Split one M-tile's 8 f32 (two f32x4) into hi/lo bf16x8 fragments.
// ---------------------------------------------------------------------------
__device__ __forceinline__ void split_tile(f32x4 A0, f32x4 A1,
                                           bf16x8& ah, bf16x8& al) {
    u32x4 hu, lu;
    hl_pair p;
    p = split_pair(A0.x, A0.y); hu.x = p.h; lu.x = p.l;
    p = split_pair(A0.z, A0.w); hu.y = p.h; lu.y = p.l;
    p = split_pair(A1.x, A1.y); hu.z = p.h; lu.z = p.l;
    p = split_pair(A1.z, A1.w); hu.w = p.h; lu.w = p.l;
    ah = __builtin_bit_cast(bf16x8, hu);
    al = __builtin_bit_cast(bf16x8, lu);
}

// ---------------------------------------------------------------------------
// One K-step, 2 M-tiles: 24 MFMAs; B fragments shared across both M-tiles.
// ---------------------------------------------------------------------------
__device__ __forceinline__ void step2(
        f32x4 A0, f32x4 A1, f32x4 A2, f32x4 A3,
        uint4 B0, uint4 B1, uint4 B2, uint4 B3,
        uint4 B4, uint4 B5, uint4 B6, uint4 B7,
        f32x4& c00, f32x4& c01, f32x4& c02, f32x4& c03,
        f32x4& c10, f32x4& c11, f32x4& c12, f32x4& c13) {
    bf16x8 ah0, al0, ah1, al1;
    split_tile(A0, A1, ah0, al0);
    split_tile(A2, A3, ah1, al1);
    bf16x8 bh, bl;
    bh = __builtin_bit_cast(bf16x8, B0); bl = __builtin_bit_cast(bf16x8, B1);
    c00 = MFMA16(ah0, bh, c00, 0, 0, 0);
    c00 = MFMA16(ah0, bl, c00, 0, 0, 0);
    c00 = MFMA16(al0, bh, c00, 0, 0, 0);
    c10 = MFMA16(ah1, bh, c10, 0, 0, 0);
    c10 = MFMA16(ah1, bl, c10, 0, 0, 0);
    c10 = MFMA16(al1, bh, c10, 0, 0, 0);
    bh = __builtin_bit_cast(bf16x8, B2); bl = __builtin_bit_cast(bf16x8, B3);
    c01 = MFMA16(ah0, bh, c01, 0, 0, 0);
    c01 = MFMA16(ah0, bl, c01, 0, 0, 0);
    c01 = MFMA16(al0, bh, c01, 0, 0, 0);
    c11 = MFMA16(ah1, bh, c11, 0, 0, 0);
    c11 = MFMA16(ah1, bl, c11, 0, 0, 0);
    c11 = MFMA16(al1, bh, c11, 0, 0, 0);
    bh = __builtin_bit_cast(bf16x8, B4); bl = __builtin_bit_cast(bf16x8, B5);
    c02 = MFMA16(ah0, bh, c02, 0, 0, 0);
    c02 = MFMA16(ah0, bl, c02, 0, 0, 0);
    c02 = MFMA16(al0, bh, c02, 0, 0, 0);
    c12 = MFMA16(ah1, bh, c12, 0, 0, 0);
    c12 = MFMA16(ah1, bl, c12, 0, 0, 0);
    c12 = MFMA16(al1, bh, c12, 0, 0, 0);
    bh = __builtin_bit_cast(bf16x8, B6); bl = __builtin_bit_cast(bf16x8, B7);
    c03 = MFMA16(ah0, bh, c03, 0, 0, 0);
    c03 = MFMA16(ah0, bl, c03, 0, 0, 0);
    c03 = MFMA16(al0, bh, c03, 0, 0, 0);
    c13 = MFMA16(ah1, bh, c13, 0, 0, 0);
    c13 = MFMA16(ah1, bl, c13, 0, 0, 0);
    c13 = MFMA16(al1, bh, c13, 0, 0, 0);
}

// ---------------------------------------------------------------------------
// Kernel 1: fused router. Block = 4 waves = 4 K-quarters of ONE 32-token
// group (2 M-tiles/wave -> B traffic halved vs 16-token). No main-loop
// barriers. x loads are non-temporal (zero reuse -> don't evict B from L2).
// Epilogue: all waves dump logits to LDS; wave kq reduces tokens kq*8..+8.
// ---------------------------------------------------------------------------
__global__ __launch_bounds__(256, 2) void router_fused(
        const float* __restrict__ x,
        const uint4* __restrict__ Bpack,
        float* __restrict__ out,
        int* __restrict__ flags) {
    __shared__ float red[4][32][64];
    const int lane = threadIdx.x & 63;
    const int kq   = threadIdx.x >> 6;        // K-quarter 0..3
    const int tok0 = blockIdx.x * 32;

    const f32x4* pa0 = (const f32x4*)x
        + (size_t)(tok0 + (lane & 15)) * (N_EMBD / 4)
        + kq * 256 + ((lane >> 4) << 1);
    const f32x4* pa1 = pa0 + (size_t)16 * (N_EMBD / 4);
    const uint4* pb = Bpack + (size_t)kq * 16384 + lane;

    f32x4 c00 = {0.f,0.f,0.f,0.f}, c01 = {0.f,0.f,0.f,0.f};
    f32x4 c02 = {0.f,0.f,0.f,0.f}, c03 = {0.f,0.f,0.f,0.f};
    f32x4 c10 = {0.f,0.f,0.f,0.f}, c11 = {0.f,0.f,0.f,0.f};
    f32x4 c12 = {0.f,0.f,0.f,0.f}, c13 = {0.f,0.f,0.f,0.f};

    uint4 ba0, ba1, ba2, ba3, ba4, ba5, ba6, ba7;
    uint4 bb0, bb1, bb2, bb3, bb4, bb5, bb6, bb7;
    f32x4 aa0, aa1, aa2, aa3, ab0, ab1, ab2, ab3;

#define LOADB(P, s) { const uint4* _q = pb + (size_t)(s) * 512;               \
    P##0 = _q[0];   P##1 = _q[64];  P##2 = _q[128]; P##3 = _q[192];           \
    P##4 = _q[256]; P##5 = _q[320]; P##6 = _q[384]; P##7 = _q[448]; }
#define LOADA(P, s) {                                                          \
    P##0 = __builtin_nontemporal_load(pa0 + (s) * 8);                          \
    P##1 = __builtin_nontemporal_load(pa0 + (s) * 8 + 1);                      \
    P##2 = __builtin_nontemporal_load(pa1 + (s) * 8);                          \
    P##3 = __builtin_nontemporal_load(pa1 + (s) * 8 + 1); }

    LOADA(aa, 0); LOADB(ba, 0);
    for (int s = 0; s < 32; s += 2) {
        LOADA(ab, s + 1); LOADB(bb, s + 1);
        step2(aa0, aa1, aa2, aa3, ba0, ba1, ba2, ba3, ba4, ba5, ba6, ba7,
              c00, c01, c02, c03, c10, c11, c12, c13);
        if (s < 30) { LOADA(aa, s + 2); LOADB(ba, s + 2); }
        step2(ab0, ab1, ab2, ab3, bb0, bb1, bb2, bb3, bb4, bb5, bb6, bb7,
              c00, c01, c02, c03, c10, c11, c12, c13);
    }
#undef LOADB
#undef LOADA

    // C layout: row(token within tile) = (lane>>4)*4 + reg, col = lane&15
    const int l15 = lane & 15;
    const int rb  = (lane >> 4) << 2;
#pragma unroll
    for (int j = 0; j < 4; ++j) {
        red[kq][rb + j][l15]      = c00[j];
        red[kq][rb + j][16 + l15] = c01[j];
        red[kq][rb + j][32 + l15] = c02[j];
        red[kq][rb + j][48 + l15] = c03[j];
        red[kq][16 + rb + j][l15]      = c10[j];
        red[kq][16 + rb + j][16 + l15] = c11[j];
        red[kq][16 + rb + j][32 + l15] = c12[j];
        red[kq][16 + rb + j][48 + l15] = c13[j];
    }
    __syncthreads();

    // wave kq reduces tokens kq*8 .. kq*8+7; lane = expert
    for (int tt = 0; tt < 8; ++tt) {
        const int t = kq * 8 + tt;
        float v = red[0][t][lane] + red[1][t][lane]
                + red[2][t][lane] + red[3][t][lane];

        float m1 = v; int i1 = lane;
#pragma unroll
        for (int off = 32; off; off >>= 1) {
            float ov = __shfl_xor(m1, off); int oi = __shfl_xor(i1, off);
            if (ov > m1 || (ov == m1 && oi < i1)) { m1 = ov; i1 = oi; }
        }
        float m2 = (lane == i1) ? -INFINITY : v; int i2 = lane;
#pragma unroll
        for (int off = 32; off; off >>= 1) {
            float ov = __shfl_xor(m2, off); int oi = __shfl_xor(i2, off);
            if (ov > m2 || (ov == m2 && oi < i2)) { m2 = ov; i2 = oi; }
        }
        float m3 = (lane == i1 || lane == i2) ? -INFINITY : v;
#pragma unroll
        for (int off = 32; off; off >>= 1)
            m3 = fmaxf(m3, __shfl_xor(m3, off));

        if (lane == 0) {
            const int tok = tok0 + t;
            float e2  = __expf(m2 - m1);
            float inv = 1.0f / (1.0f + e2);
            float2 idx = make_float2((float)i1, (float)i2);
            float2 gts = make_float2(inv, e2 * inv);
            *(float2*)(out + 2 * tok) = idx;
            *(float2*)(out + 2 * N_TOKENS + 2 * tok) = gts;
            if ((m1 - m2 < TAU) || (m2 - m3 < TAU)) {
                int p = atomicAdd(flags, 1);
                if (p < N_TOKENS) flags[1 + p] = tok;
            }
        }
    }
}

// ---------------------------------------------------------------------------
// Kernel 2: exact f64 refinement of flagged near-tie tokens. Block per token
// (grid-strided). Wave wv handles experts wv*16..+16, lanes split K.
// ---------------------------------------------------------------------------
__global__ __launch_bounds__(256) void refine(const float* __restrict__ x,
                                              const float* __restrict__ W,
                                              const int* __restrict__ flags,
                                              float* __restrict__ out) {
    __shared__ double redd[64];
    const int lane = threadIdx.x & 63;
    const int wv   = threadIdx.x >> 6;
    int cnt = flags[0];
    if (cnt > N_TOKENS) cnt = N_TOKENS;

    for (int i = blockIdx.x; i < cnt; i += gridDim.x) {
        const int tok = flags[1 + i];
        const float4* xr4 = (const float4*)(x + (size_t)tok * N_EMBD);
#pragma unroll
        for (int ee = 0; ee < 16; ++ee) {
            const int e = wv * 16 + ee;
            const float4* wr = (const float4*)(W + (size_t)e * N_EMBD);
            double acc = 0.0;
#pragma unroll 4
            for (int c = 0; c < 16; ++c) {
                float4 xv = xr4[c * 64 + lane];
                float4 wq = wr[c * 64 + lane];
                acc += (double)xv.x * wq.x + (double)xv.y * wq.y
                     + (double)xv.z * wq.z + (double)xv.w * wq.w;
            }
#pragma unroll
            for (int off = 32; off; off >>= 1)
                acc += __shfl_xor(acc, off);
            if (lane == 0) redd[e] = acc;
        }
        __syncthreads();
        if (wv == 0) {
            double v = redd[lane];
            double m1 = v; int i1 = lane;
#pragma unroll
            for (int off = 32; off; off >>= 1) {
                double ov = __shfl_xor(m1, off); int oi = __shfl_xor(i1, off);
                if (ov > m1 || (ov == m1 && oi < i1)) { m1 = ov; i1 = oi; }
            }
            double m2 = (lane == i1) ? -INFINITY : v; int i2 = lane;
#pragma unroll
            for (int off = 32; off; off >>= 1) {
                double ov = __shfl_xor(m2, off); int oi = __shfl_xor(i2, off);
                if (ov > m2 || (ov == m2 && oi < i2)) { m2 = ov; i2 = oi; }
            }
            if (lane == 0) {
                double e2  = exp(m2 - m1);
                double inv = 1.0 / (1.0 + e2);
                out[2 * tok + 0] = (float)i1;
                out[2 * tok + 1] = (float)i2;
                out[2 * N_TOKENS + 2 * tok + 0] = (float)inv;
                out[2 * N_TOKENS + 2 * tok + 1] = (float)(e2 * inv);
            }
        }
        __syncthreads();
    }
}

// ---------------------------------------------------------------------------
extern "C" void kernel_launch(void* const* d_in, const int* in_sizes, int n_in,
                              void* d_out, int out_size, void* d_ws, size_t ws_size,
                              hipStream_t stream) {
    const float* x = (const float*)d_in[0];
    const float* W = (const float*)d_in[1];
    float* out = (float*)d_out;

    uint4* Bpack = (uint4*)d_ws;                          // [0, 1MB)
    int*   flags = (int*)((char*)d_ws + (2u << 20));      // [2MB, ...)

    w_pack_bf16 <<<128, 256, 0, stream>>>(W, Bpack, flags);
    router_fused<<<N_TOKENS / 32, 256, 0, stream>>>(x, Bpack, out, flags);
    refine      <<<128, 256, 0, stream>>>(x, W, flags, out);
}

// Round 9
// 110.774 us; speedup vs baseline: 1.2438x; 1.1880x over previous
//
#include <hip/hip_runtime.h>
#include <math.h>

#define N_EMBD    4096
#define N_EXPERTS 64
#define N_TOKENS  16384
#define TAU       1e-3f
#define BM        16                  // tokens per block
#define BK        128                 // K per tile
#define NTILES    (N_EMBD / BK)       // 32

typedef __attribute__((ext_vector_type(8))) short bf16x8;
typedef __attribute__((ext_vector_type(4))) float f32x4;

#define MFMA16 __builtin_amdgcn_mfma_f32_16x16x32_bf16

struct hl_pair { unsigned h, l; };

// ---------------------------------------------------------------------------
// f32 -> (bf16 hi, bf16 lo) RNE split, pair-packed into one u32 each.
// x = hi + lo + err, |err| ~ 2^-18 |x|.
// ---------------------------------------------------------------------------
__device__ __forceinline__ hl_pair split_pair(float f0, float f1) {
    unsigned u0 = __builtin_bit_cast(unsigned, f0);
    unsigned u1 = __builtin_bit_cast(unsigned, f1);
    unsigned r0 = u0 + 0x7FFFu + ((u0 >> 16) & 1u);
    unsigned r1 = u1 + 0x7FFFu + ((u1 >> 16) & 1u);
    hl_pair p;
    p.h = (r0 >> 16) | (r1 & 0xFFFF0000u);
    float h0 = __builtin_bit_cast(float, r0 & 0xFFFF0000u);
    float h1 = __builtin_bit_cast(float, r1 & 0xFFFF0000u);
    float l0 = f0 - h0;
    float l1 = f1 - h1;
    unsigned v0 = __builtin_bit_cast(unsigned, l0);
    unsigned v1 = __builtin_bit_cast(unsigned, l1);
    unsigned s0 = v0 + 0x7FFFu + ((v0 >> 16) & 1u);
    unsigned s1 = v1 + 0x7FFFu + ((v1 >> 16) & 1u);
    p.l = (s0 >> 16) | (s1 & 0xFFFF0000u);
    return p;
}

// ---------------------------------------------------------------------------
// Kernel 0: pack W into bf16 hi/lo MFMA B-fragments; zero the flag counter.
// Frag F = ks*8 + nt*2 + term. Lane l elem j = W[nt*16+(l&15)][ks*32+(l>>4)*8+j]
// ---------------------------------------------------------------------------
__global__ void w_pack_bf16(const float* __restrict__ W,
                            uint4* __restrict__ Bpack,
                            int* __restrict__ flags) {
    int tid = blockIdx.x * blockDim.x + threadIdx.x;   // 32768
    if (tid == 0) flags[0] = 0;
    int lane = tid & 63;
    int nt   = (tid >> 6) & 3;
    int ks   = tid >> 8;                               // 0..127
    int e = nt * 16 + (lane & 15);
    int k = ks * 32 + ((lane >> 4) << 3);
    const float* src = W + (size_t)e * N_EMBD + k;
    uint4 hp, lp;
    hl_pair p0 = split_pair(src[0], src[1]);
    hl_pair p1 = split_pair(src[2], src[3]);
    hl_pair p2 = split_pair(src[4], src[5]);
    hl_pair p3 = split_pair(src[6], src[7]);
    hp.x = p0.h; lp.x = p0.l;
    hp.y = p1.h; lp.y = p1.l;
    hp.z = p2.h; lp.z = p2.l;
    hp.w = p3.h; lp.w = p3.l;
    size_t F = (size_t)ks * 8 + nt * 2;
    Bpack[F * 64 + lane]       = hp;
    Bpack[(F + 1) * 64 + lane] = lp;
}

// ---------------------------------------------------------------------------
// Split one float4 of x into bf16 hi/lo and store to swizzled LDS planes.
// hi plane at [0,4096), lo plane at [4096,8192). off = swizzled byte offset.
// ---------------------------------------------------------------------------
__device__ __forceinline__ void store_split(char* ldsA, int off, f32x4 v) {
    hl_pair p01 = split_pair(v.x, v.y);
    hl_pair p23 = split_pair(v.z, v.w);
    uint2 hw, lw;
    hw.x = p01.h; hw.y = p23.h;
    lw.x = p01.l; lw.y = p23.l;
    *(uint2*)(ldsA + off)        = hw;
    *(uint2*)(ldsA + off + 4096) = lw;
}

// ---------------------------------------------------------------------------
// Kernel 1: fused router, canonical LDS-staged form.
// Block = 16 tokens x 4 waves; wave w owns experts [w*16, w*16+16).
// Per K-tile: coalesced f32 loads -> split -> swizzled LDS planes
// (T14: next tile's loads issued before compute) -> ds_read_b128 fragments
// + B frags from L2 -> 3 MFMA per K-step. Epilogue: LDS combine + top-3
// butterflies + softmax + near-tie flagging.
// Swizzle discipline (rule #21): physical = logical ^ ((row&7)<<4), applied
// to the FULL logical byte offset on BOTH write and read sides.
// ---------------------------------------------------------------------------
__global__ __launch_bounds__(256, 3) void router_fused(
        const float* __restrict__ x,
        const uint4* __restrict__ Bpack,
        float* __restrict__ out,
        int* __restrict__ flags) {
    __shared__ __align__(16) char ldsA[8192];   // hi/lo planes [16][128] bf16, swizzled
    __shared__ float red[BM][64];

    const int tid  = threadIdx.x;
    const int lane = tid & 63;
    const int w    = tid >> 6;                  // wave = expert quarter
    const int tok0 = blockIdx.x * BM;

    // staging geometry: thread covers rows {row0, row0+8}, float4 col k4
    const int k4   = tid & 31;
    const int row0 = tid >> 5;                  // 0..7
    const f32x4* g0 = (const f32x4*)x + (size_t)(tok0 + row0) * (N_EMBD / 4) + k4;
    const f32x4* g1 = g0 + 8 * (N_EMBD / 4);
    const int swz = (row0 & 7) << 4;            // same for row0 and row0+8
    const int wo0 = ((row0    ) * 256 + k4 * 8) ^ swz;
    const int wo1 = ((row0 + 8) * 256 + k4 * 8) ^ swz;

    // fragment read: lane l -> row l&15, byte col l16*16 + ksl*64, then XOR
    const int l15 = lane & 15, l16 = lane >> 4;
    const int ro_base = l15 * 256 + l16 * 16;
    const int swz_r   = (l15 & 7) << 4;

    f32x4 acc = {0.f, 0.f, 0.f, 0.f};

    f32x4 r0 = g0[0];
    f32x4 r1 = g1[0];
    for (int t = 0; t < NTILES; ++t) {
        __syncthreads();                        // prev tile's readers done
        store_split(ldsA, wo0, r0);
        store_split(ldsA, wo1, r1);
        if (t + 1 < NTILES) {                   // T14: issue next tile early
            r0 = g0[(t + 1) * (BK / 4)];
            r1 = g1[(t + 1) * (BK / 4)];
        }
        __syncthreads();                        // LDS planes ready
#pragma unroll
        for (int ksl = 0; ksl < 4; ++ksl) {
            const uint4* bq = Bpack + ((size_t)(t * 4 + ksl) * 8 + w * 2) * 64 + lane;
            uint4 bhq = bq[0];
            uint4 blq = bq[64];
            const int off = (ro_base + ksl * 64) ^ swz_r;   // full-logical XOR
            bf16x8 ah = *(const bf16x8*)(ldsA + off);
            bf16x8 al = *(const bf16x8*)(ldsA + off + 4096);
            bf16x8 bh = __builtin_bit_cast(bf16x8, bhq);
            bf16x8 bl = __builtin_bit_cast(bf16x8, blq);
            acc = MFMA16(ah, bh, acc, 0, 0, 0);
            acc = MFMA16(ah, bl, acc, 0, 0, 0);
            acc = MFMA16(al, bh, acc, 0, 0, 0);
        }
    }

    // C layout: row(token) = (lane>>4)*4 + reg, col(expert in quarter) = lane&15
    const int rb = l16 << 2;
#pragma unroll
    for (int j = 0; j < 4; ++j)
        red[rb + j][w * 16 + l15] = acc[j];
    __syncthreads();

    // wave w finalizes tokens w*4 .. w*4+3; lane = expert
    for (int tt = 0; tt < 4; ++tt) {
        const int t = w * 4 + tt;
        float v = red[t][lane];

        float m1 = v; int i1 = lane;
#pragma unroll
        for (int off = 32; off; off >>= 1) {
            float ov = __shfl_xor(m1, off); int oi = __shfl_xor(i1, off);
            if (ov > m1 || (ov == m1 && oi < i1)) { m1 = ov; i1 = oi; }
        }
        float m2 = (lane == i1) ? -INFINITY : v; int i2 = lane;
#pragma unroll
        for (int off = 32; off; off >>= 1) {
            float ov = __shfl_xor(m2, off); int oi = __shfl_xor(i2, off);
            if (ov > m2 || (ov == m2 && oi < i2)) { m2 = ov; i2 = oi; }
        }
        float m3 = (lane == i1 || lane == i2) ? -INFINITY : v;
#pragma unroll
        for (int off = 32; off; off >>= 1)
            m3 = fmaxf(m3, __shfl_xor(m3, off));

        if (lane == 0) {
            const int tok = tok0 + t;
            float e2  = __expf(m2 - m1);
            float inv = 1.0f / (1.0f + e2);
            float2 idx = make_float2((float)i1, (float)i2);
            float2 gts = make_float2(inv, e2 * inv);
            *(float2*)(out + 2 * tok) = idx;
            *(float2*)(out + 2 * N_TOKENS + 2 * tok) = gts;
            if ((m1 - m2 < TAU) || (m2 - m3 < TAU)) {
                int p = atomicAdd(flags, 1);
                if (p < N_TOKENS) flags[1 + p] = tok;
            }
        }
    }
}

// ---------------------------------------------------------------------------
// Kernel 2: exact f64 refinement of flagged near-tie tokens. Block per token
// (grid-strided). Wave wv handles experts wv*16..+16, lanes split K.
// ---------------------------------------------------------------------------
__global__ __launch_bounds__(256) void refine(const float* __restrict__ x,
                                              const float* __restrict__ W,
                                              const int* __restrict__ flags,
                                              float* __restrict__ out) {
    __shared__ double redd[64];
    const int lane = threadIdx.x & 63;
    const int wv   = threadIdx.x >> 6;
    int cnt = flags[0];
    if (cnt > N_TOKENS) cnt = N_TOKENS;

    for (int i = blockIdx.x; i < cnt; i += gridDim.x) {
        const int tok = flags[1 + i];
        const float4* xr4 = (const float4*)(x + (size_t)tok * N_EMBD);
#pragma unroll
        for (int ee = 0; ee < 16; ++ee) {
            const int e = wv * 16 + ee;
            const float4* wr = (const float4*)(W + (size_t)e * N_EMBD);
            double acc = 0.0;
#pragma unroll 4
            for (int c = 0; c < 16; ++c) {
                float4 xv = xr4[c * 64 + lane];
                float4 wq = wr[c * 64 + lane];
                acc += (double)xv.x * wq.x + (double)xv.y * wq.y
                     + (double)xv.z * wq.z + (double)xv.w * wq.w;
            }
#pragma unroll
            for (int off = 32; off; off >>= 1)
                acc += __shfl_xor(acc, off);
            if (lane == 0) redd[e] = acc;
        }
        __syncthreads();
        if (wv == 0) {
            double v = redd[lane];
            double m1 = v; int i1 = lane;
#pragma unroll
            for (int off = 32; off; off >>= 1) {
                double ov = __shfl_xor(m1, off); int oi = __shfl_xor(i1, off);
                if (ov > m1 || (ov == m1 && oi < i1)) { m1 = ov; i1 = oi; }
            }
            double m2 = (lane == i1) ? -INFINITY : v; int i2 = lane;
#pragma unroll
            for (int off = 32; off; off >>= 1) {
                double ov = __shfl_xor(m2, off); int oi = __shfl_xor(i2, off);
                if (ov > m2 || (ov == m2 && oi < i2)) { m2 = ov; i2 = oi; }
            }
            if (lane == 0) {
                double e2  = exp(m2 - m1);
                double inv = 1.0 / (1.0 + e2);
                out[2 * tok + 0] = (float)i1;
                out[2 * tok + 1] = (float)i2;
                out[2 * N_TOKENS + 2 * tok + 0] = (float)inv;
                out[2 * N_TOKENS + 2 * tok + 1] = (float)(e2 * inv);
            }
        }
        __syncthreads();
    }
}

// ---------------------------------------------------------------------------
extern "C" void kernel_launch(void* const* d_in, const int* in_sizes, int n_in,
                              void* d_out, int out_size, void* d_ws, size_t ws_size,
                              hipStream_t stream) {
    const float* x = (const float*)d_in[0];
    const float* W = (const float*)d_in[1];
    float* out = (float*)d_out;

    uint4* Bpack = (uint4*)d_ws;                          // [0, 1MB)
    int*   flags = (int*)((char*)d_ws + (2u << 20));      // [2MB, ...)

    w_pack_bf16 <<<128, 256, 0, stream>>>(W, Bpack, flags);
    router_fused<<<N_TOKENS / BM, 256, 0, stream>>>(x, Bpack, out, flags);
    refine      <<<128, 256, 0, stream>>>(x, W, flags, out);
}

// Round 10
// 105.707 us; speedup vs baseline: 1.3034x; 1.0479x over previous
//
#include <hip/hip_runtime.h>
#include <math.h>

#define N_EMBD    4096
#define N_EXPERTS 64
#define N_TOKENS  16384
#define TAU       1e-3f
#define BM        16                  // tokens per block
#define BK        128                 // K per tile
#define NTILES    (N_EMBD / BK)       // 32

typedef __attribute__((ext_vector_type(8))) short bf16x8;
typedef __attribute__((ext_vector_type(4))) float f32x4;

#define MFMA16 __builtin_amdgcn_mfma_f32_16x16x32_bf16

struct hl_pair { unsigned h, l; };

// ---------------------------------------------------------------------------
// f32 -> (bf16 hi, bf16 lo) RNE split, pair-packed into one u32 each.
// x = hi + lo + err, |err| ~ 2^-18 |x|.
// ---------------------------------------------------------------------------
__device__ __forceinline__ hl_pair split_pair(float f0, float f1) {
    unsigned u0 = __builtin_bit_cast(unsigned, f0);
    unsigned u1 = __builtin_bit_cast(unsigned, f1);
    unsigned r0 = u0 + 0x7FFFu + ((u0 >> 16) & 1u);
    unsigned r1 = u1 + 0x7FFFu + ((u1 >> 16) & 1u);
    hl_pair p;
    p.h = (r0 >> 16) | (r1 & 0xFFFF0000u);
    float h0 = __builtin_bit_cast(float, r0 & 0xFFFF0000u);
    float h1 = __builtin_bit_cast(float, r1 & 0xFFFF0000u);
    float l0 = f0 - h0;
    float l1 = f1 - h1;
    unsigned v0 = __builtin_bit_cast(unsigned, l0);
    unsigned v1 = __builtin_bit_cast(unsigned, l1);
    unsigned s0 = v0 + 0x7FFFu + ((v0 >> 16) & 1u);
    unsigned s1 = v1 + 0x7FFFu + ((v1 >> 16) & 1u);
    p.l = (s0 >> 16) | (s1 & 0xFFFF0000u);
    return p;
}

// ---------------------------------------------------------------------------
// Kernel 0: pack W into bf16 hi/lo MFMA B-fragments; zero the flag counter.
// Frag F = ks*8 + nt*2 + term. Lane l elem j = W[nt*16+(l&15)][ks*32+(l>>4)*8+j]
// ---------------------------------------------------------------------------
__global__ void w_pack_bf16(const float* __restrict__ W,
                            uint4* __restrict__ Bpack,
                            int* __restrict__ flags) {
    int tid = blockIdx.x * blockDim.x + threadIdx.x;   // 32768
    if (tid == 0) flags[0] = 0;
    int lane = tid & 63;
    int nt   = (tid >> 6) & 3;
    int ks   = tid >> 8;                               // 0..127
    int e = nt * 16 + (lane & 15);
    int k = ks * 32 + ((lane >> 4) << 3);
    const float* src = W + (size_t)e * N_EMBD + k;
    uint4 hp, lp;
    hl_pair p0 = split_pair(src[0], src[1]);
    hl_pair p1 = split_pair(src[2], src[3]);
    hl_pair p2 = split_pair(src[4], src[5]);
    hl_pair p3 = split_pair(src[6], src[7]);
    hp.x = p0.h; lp.x = p0.l;
    hp.y = p1.h; lp.y = p1.l;
    hp.z = p2.h; lp.z = p2.l;
    hp.w = p3.h; lp.w = p3.l;
    size_t F = (size_t)ks * 8 + nt * 2;
    Bpack[F * 64 + lane]       = hp;
    Bpack[(F + 1) * 64 + lane] = lp;
}

// ---------------------------------------------------------------------------
// Split one float4 of x into bf16 hi/lo and store to swizzled LDS planes.
// hi plane at buf+[0,4096), lo plane at buf+[4096,8192).
// ---------------------------------------------------------------------------
__device__ __forceinline__ void store_split(char* buf, int off, f32x4 v) {
    hl_pair p01 = split_pair(v.x, v.y);
    hl_pair p23 = split_pair(v.z, v.w);
    uint2 hw, lw;
    hw.x = p01.h; hw.y = p23.h;
    lw.x = p01.l; lw.y = p23.l;
    *(uint2*)(buf + off)        = hw;
    *(uint2*)(buf + off + 4096) = lw;
}

// ---------------------------------------------------------------------------
// Kernel 1: fused router — double-buffered LDS + raw-barrier pipeline.
// Block = 16 tokens x 4 waves; wave w owns experts [w*16, w*16+16).
// Per tile: hoisted B-loads (L2) + ds_read fragments + 12 MFMA, then
// store next tile's A (vmcnt wait lands HERE, covered by compute), then
// issue A-loads for t+2, then lgkmcnt(0) + raw s_barrier (NO vmcnt drain
// -> A-loads stay in flight across the barrier; the __syncthreads full
// drain was the r9 stall). Single barrier per tile (dbuf; lgkmcnt(0)
// covers both ds_reads and ds_writes of the leaving wave).
// Swizzle: physical = logical ^ ((row&7)<<4) on both sides (rule #21).
// ---------------------------------------------------------------------------
__global__ __launch_bounds__(256, 4) void router_fused(
        const float* __restrict__ x,
        const uint4* __restrict__ Bpack,
        float* __restrict__ out,
        int* __restrict__ flags) {
    __shared__ __align__(16) char ldsA[2 * 8192];   // 2 bufs x {hi,lo} planes
    __shared__ float red[BM][64];

    const int tid  = threadIdx.x;
    const int lane = tid & 63;
    const int w    = tid >> 6;                  // wave = expert quarter
    const int tok0 = blockIdx.x * BM;

    // staging geometry: thread covers rows {row0, row0+8}, float4 col k4
    const int k4   = tid & 31;
    const int row0 = tid >> 5;                  // 0..7
    const f32x4* g0 = (const f32x4*)x + (size_t)(tok0 + row0) * (N_EMBD / 4) + k4;
    const f32x4* g1 = g0 + 8 * (N_EMBD / 4);
    const int swz = (row0 & 7) << 4;
    const int wo0 = ((row0    ) * 256 + k4 * 8) ^ swz;
    const int wo1 = ((row0 + 8) * 256 + k4 * 8) ^ swz;

    // fragment read: lane l -> row l&15, byte col l16*16 + ksl*64, full XOR
    const int l15 = lane & 15, l16 = lane >> 4;
    const int ro_base = l15 * 256 + l16 * 16;
    const int swz_r   = (l15 & 7) << 4;
    const int off0 = (ro_base +   0) ^ swz_r;
    const int off1 = (ro_base +  64) ^ swz_r;
    const int off2 = (ro_base + 128) ^ swz_r;
    const int off3 = (ro_base + 192) ^ swz_r;

    f32x4 acc = {0.f, 0.f, 0.f, 0.f};

    // prologue: stage tile 0, issue loads for tile 1
    f32x4 r0 = g0[0];
    f32x4 r1 = g1[0];
    store_split(ldsA, wo0, r0);
    store_split(ldsA, wo1, r1);
    r0 = g0[BK / 4];
    r1 = g1[BK / 4];
    asm volatile("s_waitcnt lgkmcnt(0)" ::: "memory");
    __builtin_amdgcn_s_barrier();
    __builtin_amdgcn_sched_barrier(0);

    for (int t = 0; t < NTILES; ++t) {
        char* bufr = ldsA + (t & 1) * 8192;
        char* bufw = ldsA + ((t & 1) ^ 1) * 8192;

        // B fragments for this tile (8 x 1KB wave-loads from L2), hoisted
        const uint4* bq = Bpack + ((size_t)(t * 4) * 8 + w * 2) * 64 + lane;
        uint4 bh0 = bq[0];    uint4 bl0 = bq[64];
        uint4 bh1 = bq[512];  uint4 bl1 = bq[576];
        uint4 bh2 = bq[1024]; uint4 bl2 = bq[1088];
        uint4 bh3 = bq[1536]; uint4 bl3 = bq[1600];

        bf16x8 ah, al;
        ah = *(const bf16x8*)(bufr + off0);
        al = *(const bf16x8*)(bufr + off0 + 4096);
        acc = MFMA16(ah, __builtin_bit_cast(bf16x8, bh0), acc, 0, 0, 0);
        acc = MFMA16(ah, __builtin_bit_cast(bf16x8, bl0), acc, 0, 0, 0);
        acc = MFMA16(al, __builtin_bit_cast(bf16x8, bh0), acc, 0, 0, 0);
        ah = *(const bf16x8*)(bufr + off1);
        al = *(const bf16x8*)(bufr + off1 + 4096);
        acc = MFMA16(ah, __builtin_bit_cast(bf16x8, bh1), acc, 0, 0, 0);
        acc = MFMA16(ah, __builtin_bit_cast(bf16x8, bl1), acc, 0, 0, 0);
        acc = MFMA16(al, __builtin_bit_cast(bf16x8, bh1), acc, 0, 0, 0);
        ah = *(const bf16x8*)(bufr + off2);
        al = *(const bf16x8*)(bufr + off2 + 4096);
        acc = MFMA16(ah, __builtin_bit_cast(bf16x8, bh2), acc, 0, 0, 0);
        acc = MFMA16(ah, __builtin_bit_cast(bf16x8, bl2), acc, 0, 0, 0);
        acc = MFMA16(al, __builtin_bit_cast(bf16x8, bh2), acc, 0, 0, 0);
        ah = *(const bf16x8*)(bufr + off3);
        al = *(const bf16x8*)(bufr + off3 + 4096);
        acc = MFMA16(ah, __builtin_bit_cast(bf16x8, bh3), acc, 0, 0, 0);
        acc = MFMA16(ah, __builtin_bit_cast(bf16x8, bl3), acc, 0, 0, 0);
        acc = MFMA16(al, __builtin_bit_cast(bf16x8, bh3), acc, 0, 0, 0);

        if (t + 1 < NTILES) {
            store_split(bufw, wo0, r0);         // vmcnt wait for r0/r1 here
            store_split(bufw, wo1, r1);
            if (t + 2 < NTILES) {
                r0 = g0[(t + 2) * (BK / 4)];    // stays in flight across barrier
                r1 = g1[(t + 2) * (BK / 4)];
            }
            asm volatile("s_waitcnt lgkmcnt(0)" ::: "memory");
            __builtin_amdgcn_s_barrier();
            __builtin_amdgcn_sched_barrier(0);
        }
    }

    // C layout: row(token) = (lane>>4)*4 + reg, col(expert in quarter) = lane&15
    const int rb = l16 << 2;
#pragma unroll
    for (int j = 0; j < 4; ++j)
        red[rb + j][w * 16 + l15] = acc[j];
    __syncthreads();

    // wave w finalizes tokens w*4 .. w*4+3; lane = expert
    for (int tt = 0; tt < 4; ++tt) {
        const int t = w * 4 + tt;
        float v = red[t][lane];

        float m1 = v; int i1 = lane;
#pragma unroll
        for (int off = 32; off; off >>= 1) {
            float ov = __shfl_xor(m1, off); int oi = __shfl_xor(i1, off);
            if (ov > m1 || (ov == m1 && oi < i1)) { m1 = ov; i1 = oi; }
        }
        float m2 = (lane == i1) ? -INFINITY : v; int i2 = lane;
#pragma unroll
        for (int off = 32; off; off >>= 1) {
            float ov = __shfl_xor(m2, off); int oi = __shfl_xor(i2, off);
            if (ov > m2 || (ov == m2 && oi < i2)) { m2 = ov; i2 = oi; }
        }
        float m3 = (lane == i1 || lane == i2) ? -INFINITY : v;
#pragma unroll
        for (int off = 32; off; off >>= 1)
            m3 = fmaxf(m3, __shfl_xor(m3, off));

        if (lane == 0) {
            const int tok = tok0 + t;
            float e2  = __expf(m2 - m1);
            float inv = 1.0f / (1.0f + e2);
            float2 idx = make_float2((float)i1, (float)i2);
            float2 gts = make_float2(inv, e2 * inv);
            *(float2*)(out + 2 * tok) = idx;
            *(float2*)(out + 2 * N_TOKENS + 2 * tok) = gts;
            if ((m1 - m2 < TAU) || (m2 - m3 < TAU)) {
                int p = atomicAdd(flags, 1);
                if (p < N_TOKENS) flags[1 + p] = tok;
            }
        }
    }
}

// ---------------------------------------------------------------------------
// Kernel 2: exact f64 refinement of flagged near-tie tokens. Block per token
// (grid-strided). Wave wv handles experts wv*16..+16, lanes split K.
// ---------------------------------------------------------------------------
__global__ __launch_bounds__(256) void refine(const float* __restrict__ x,
                                              const float* __restrict__ W,
                                              const int* __restrict__ flags,
                                              float* __restrict__ out) {
    __shared__ double redd[64];
    const int lane = threadIdx.x & 63;
    const int wv   = threadIdx.x >> 6;
    int cnt = flags[0];
    if (cnt > N_TOKENS) cnt = N_TOKENS;

    for (int i = blockIdx.x; i < cnt; i += gridDim.x) {
        const int tok = flags[1 + i];
        const float4* xr4 = (const float4*)(x + (size_t)tok * N_EMBD);
#pragma unroll
        for (int ee = 0; ee < 16; ++ee) {
            const int e = wv * 16 + ee;
            const float4* wr = (const float4*)(W + (size_t)e * N_EMBD);
            double acc = 0.0;
#pragma unroll 4
            for (int c = 0; c < 16; ++c) {
                float4 xv = xr4[c * 64 + lane];
                float4 wq = wr[c * 64 + lane];
                acc += (double)xv.x * wq.x + (double)xv.y * wq.y
                     + (double)xv.z * wq.z + (double)xv.w * wq.w;
            }
#pragma unroll
            for (int off = 32; off; off >>= 1)
                acc += __shfl_xor(acc, off);
            if (lane == 0) redd[e] = acc;
        }
        __syncthreads();
        if (wv == 0) {
            double v = redd[lane];
            double m1 = v; int i1 = lane;
#pragma unroll
            for (int off = 32; off; off >>= 1) {
                double ov = __shfl_xor(m1, off); int oi = __shfl_xor(i1, off);
                if (ov > m1 || (ov == m1 && oi < i1)) { m1 = ov; i1 = oi; }
            }
            double m2 = (lane == i1) ? -INFINITY : v; int i2 = lane;
#pragma unroll
            for (int off = 32; off; off >>= 1) {
                double ov = __shfl_xor(m2, off); int oi = __shfl_xor(i2, off);
                if (ov > m2 || (ov == m2 && oi < i2)) { m2 = ov; i2 = oi; }
            }
            if (lane == 0) {
                double e2  = exp(m2 - m1);
                double inv = 1.0 / (1.0 + e2);
                out[2 * tok + 0] = (float)i1;
                out[2 * tok + 1] = (float)i2;
                out[2 * N_TOKENS + 2 * tok + 0] = (float)inv;
                out[2 * N_TOKENS + 2 * tok + 1] = (float)(e2 * inv);
            }
        }
        __syncthreads();
    }
}

// ---------------------------------------------------------------------------
extern "C" void kernel_launch(void* const* d_in, const int* in_sizes, int n_in,
                              void* d_out, int out_size, void* d_ws, size_t ws_size,
                              hipStream_t stream) {
    const float* x = (const float*)d_in[0];
    const float* W = (const float*)d_in[1];
    float* out = (float*)d_out;

    uint4* Bpack = (uint4*)d_ws;                          // [0, 1MB)
    int*   flags = (int*)((char*)d_ws + (2u << 20));      // [2MB, ...)

    w_pack_bf16 <<<128, 256, 0, stream>>>(W, Bpack, flags);
    router_fused<<<N_TOKENS / BM, 256, 0, stream>>>(x, Bpack, out, flags);
    refine      <<<128, 256, 0, stream>>>(x, W, flags, out);
}